// Round 11
// baseline (1540.058 us; speedup 1.0000x reference)
//
#include <hip/hip_runtime.h>
#include <cstdint>
#include <cstddef>

#define NN 131072
#define EE 524288
#define GG 4096
#define NPASS 4

typedef __attribute__((ext_vector_type(4))) float f32x4;
typedef __attribute__((ext_vector_type(8))) short bfrag;

__device__ __forceinline__ unsigned short f2bf(float f) {
  union { float f; unsigned u; } v; v.f = f;
  unsigned r = v.u + 0x7fffu + ((v.u >> 16) & 1u);
  return (unsigned short)(r >> 16);
}
__device__ __forceinline__ float bf2f(unsigned short h) {
  union { unsigned u; float f; } v; v.u = ((unsigned)h) << 16;
  return v.f;
}
__device__ __forceinline__ unsigned pack2(float x, float y) {
  return (unsigned)f2bf(x) | ((unsigned)f2bf(y) << 16);
}
__device__ __forceinline__ float sigm(float x) { return 1.f / (1.f + __expf(-x)); }

// async global->LDS 16B: LDS dest is wave-uniform base + lane*16
__device__ __forceinline__ void cp16(unsigned short* l, const unsigned short* g) {
  __builtin_amdgcn_global_load_lds(
      (const __attribute__((address_space(1))) unsigned int*)g,
      (__attribute__((address_space(3))) unsigned int*)l, 16, 0, 0);
}

// ---------------- weight prep ----------------
__global__ void prep_wb(const float* __restrict__ Wmsg, unsigned short* __restrict__ Wb) {
  int idx = blockIdx.x * 256 + threadIdx.x;  // 256*512
  if (idx >= 256 * 512) return;
  int m = idx >> 9, k = idx & 511;
  int t = k >> 7, d = k & 127;
  Wb[idx] = f2bf(Wmsg[((size_t)t * 256 + m) * 128 + d]);
}

// Wgru rows interleaved by gate: out-col = 4*d + g, g in {r,z,n,hn}
__global__ void prep_wgru(const float* __restrict__ Wih, const float* __restrict__ Whh,
                          unsigned short* __restrict__ Wgru) {
  int idx = blockIdx.x * 256 + threadIdx.x;  // 512*384
  if (idx >= 512 * 384) return;
  int j = idx / 384, kk = idx % 384;
  float v;
  if (kk < 256) v = (j < 384) ? Wih[j * 256 + kk] : 0.f;
  else          v = (j < 256) ? Whh[j * 128 + (kk - 256)]
                   : ((j >= 384) ? Whh[(j - 128) * 128 + (kk - 256)] : 0.f);
  int g = (j < 128) ? 0 : (j < 256) ? 1 : (j < 384) ? 2 : 3;
  int d = j & 127;
  Wgru[(size_t)(4 * d + g) * 384 + kk] = f2bf(v);
}

__global__ void prep_bias(const float* __restrict__ bih, const float* __restrict__ bhh,
                          float* __restrict__ biasg) {
  int j = blockIdx.x * 256 + threadIdx.x;
  if (j >= 512) return;
  float v;
  if (j < 256) v = bih[j] + bhh[j];
  else if (j < 384) v = bih[j];
  else v = bhh[j - 128];
  int g = (j < 128) ? 0 : (j < 256) ? 1 : (j < 384) ? 2 : 3;
  int d = j & 127;
  biasg[4 * d + g] = v;
}

// WcT[d*256 + j] = sum_k Wx[j][k] * Wn2g[k*128+d], Wx = [Wloc; Wlv] (fp32)
__global__ void compose_k(const float* __restrict__ Wloc, const float* __restrict__ Wlv,
                          const float* __restrict__ Wn2g, float* __restrict__ WcT) {
  int b = blockIdx.x;  // 128 blocks
  int jl = threadIdx.x >> 7, d = threadIdx.x & 127;
  int j = b * 2 + jl;
  const float* wx = (j < 128) ? Wloc + (size_t)j * 512 : Wlv + (size_t)(j - 128) * 512;
  float acc = 0.f;
  for (int k = 0; k < 512; k++) acc += wx[k] * Wn2g[k * 128 + d];
  WcT[d * 256 + j] = acc;
}

__global__ void cvec_k(const float* __restrict__ Wloc, const float* __restrict__ Wlv,
                       const float* __restrict__ bn2g, float* __restrict__ cvec) {
  int j = threadIdx.x;  // 256
  const float* wx = (j < 128) ? Wloc + (size_t)j * 512 : Wlv + (size_t)(j - 128) * 512;
  float a = 0.f;
  for (int k = 0; k < 512; k++) a += wx[k] * bn2g[k];
  cvec[j] = a;
}

// ---------------- init ----------------
__global__ void init_h(const int* __restrict__ nt, const float* __restrict__ emb,
                       unsigned short* __restrict__ H) {
  size_t idx = (size_t)blockIdx.x * 256 + threadIdx.x;  // N*128
  int n = (int)(idx >> 7), d = (int)(idx & 127);
  H[idx] = f2bf(emb[(size_t)nt[n] * 128 + d]);
}

// ---------------- CSR build (once per call) ----------------
// single atomic pass: cnti[n*4+t]++
__global__ void cnt4_k(const int* __restrict__ edst, const int* __restrict__ etype,
                       int* __restrict__ cnti) {
  int e = blockIdx.x * 256 + threadIdx.x;
  if (e >= EE) return;
  atomicAdd(&cnti[edst[e] * 4 + etype[e]], 1);
}

__global__ void cvt_k(const int* __restrict__ cnti, float* __restrict__ cnt) {
  int i = blockIdx.x * 256 + threadIdx.x;  // 4N
  if (i >= 4 * NN) return;
  cnt[i] = (float)cnti[i];
}

__global__ __launch_bounds__(1024) void scan_k(const int* __restrict__ cnti,
                                               int* __restrict__ rowptr,
                                               int* __restrict__ cursor) {
  __shared__ int part[1024];
  int t = threadIdx.x;
  int base = t * 128;
  int s = 0;
  for (int i = 0; i < 128; i++) {
    const int* c4 = &cnti[(base + i) * 4];
    s += c4[0] + c4[1] + c4[2] + c4[3];
  }
  part[t] = s;
  __syncthreads();
  for (int off = 1; off < 1024; off <<= 1) {
    int v = (t >= off) ? part[t - off] : 0;
    __syncthreads();
    part[t] += v;
    __syncthreads();
  }
  int run = part[t] - s;  // exclusive prefix
  for (int i = 0; i < 128; i++) {
    rowptr[base + i] = run;
    cursor[base + i] = run;
    const int* c4 = &cnti[(base + i) * 4];
    run += c4[0] + c4[1] + c4[2] + c4[3];
  }
  if (t == 1023) rowptr[NN] = run;
}

__global__ void fill_k(const int* __restrict__ esrc, const int* __restrict__ edst,
                       const int* __restrict__ etype, int* __restrict__ cursor,
                       unsigned* __restrict__ epack) {
  int e = blockIdx.x * 256 + threadIdx.x;
  if (e >= EE) return;
  int pos = atomicAdd(&cursor[edst[e]], 1);
  epack[pos] = ((unsigned)etype[e] << 17) | (unsigned)esrc[e];
}

// ---------------- per-pass aggregation: s[n, t*128+d] = sum h[src] (bf16 out) ----------------
__global__ __launch_bounds__(256) void agg_k(const int* __restrict__ rowptr,
                                             const unsigned* __restrict__ epack,
                                             const unsigned short* __restrict__ H,
                                             unsigned short* __restrict__ s) {
  int n = blockIdx.x * 4 + (threadIdx.x >> 6);
  int lane = threadIdx.x & 63;
  int beg = rowptr[n], end = rowptr[n + 1];
  const unsigned short* hbase = H + lane * 2;
  float a0 = 0.f, a1 = 0.f, b0 = 0.f, b1 = 0.f;
  float c0 = 0.f, c1 = 0.f, d0 = 0.f, d1 = 0.f;
  for (int base = beg; base < end; base += 64) {
    int cnt = end - base;
    if (cnt > 64) cnt = 64;
    int mye = base + lane;
    unsigned ep = (mye < end) ? epack[mye] : 0u;  // coalesced pre-load
    for (int j = 0; j < cnt; j++) {
      unsigned p = (unsigned)__shfl((int)ep, j);  // wave-uniform edge
      int src = (int)(p & 0x1FFFFu);
      int t = (int)(p >> 17);
      unsigned hv = *(const unsigned*)&hbase[(size_t)src * 128];
      float v0 = bf2f((unsigned short)(hv & 0xffffu));
      float v1 = bf2f((unsigned short)(hv >> 16));
      if (t == 0)      { a0 += v0; a1 += v1; }
      else if (t == 1) { b0 += v0; b1 += v1; }
      else if (t == 2) { c0 += v0; c1 += v1; }
      else             { d0 += v0; d1 += v1; }
    }
  }
  unsigned short* srow = s + (size_t)n * 512;
  *(unsigned*)&srow[0 * 128 + lane * 2] = pack2(a0, a1);
  *(unsigned*)&srow[1 * 128 + lane * 2] = pack2(b0, b1);
  *(unsigned*)&srow[2 * 128 + lane * 2] = pack2(c0, c1);
  *(unsigned*)&srow[3 * 128 + lane * 2] = pack2(d0, d1);
}

// ---------------- fused m+GRU GEMM: 64 rows/block, single-buffer staging, 3 blocks/CU ----
// phase B: m = relu(s @ Wb^T + cnt*b_msg) -> LDS mT (stride 264)
// phase C: GRU GEMM [m | H] @ Wgru^T (cols gate-interleaved 4*d+g), 2 jh halves,
//          quad-transpose GRU epilogue -> Hn.
// LDS = mT 33792 + stg 20480 = 54272 B -> 3 blocks/CU (162816 <= 163840).
__global__ __launch_bounds__(256, 3) void mgru_k(
    const unsigned short* __restrict__ s, const float* __restrict__ cnt,
    const unsigned short* __restrict__ Hc, unsigned short* __restrict__ Hn,
    const unsigned short* __restrict__ Wb, const unsigned short* __restrict__ Wgru,
    const float* __restrict__ bmsg, const float* __restrict__ biasg) {
  __shared__ __align__(16) unsigned short mT[64 * 264];  // 33792 B
  __shared__ __align__(16) unsigned short stg[10240];    // As[0,2048) Ws[2048,10240)
  int i0 = blockIdx.x * 64;
  int tid = threadIdx.x, lane = tid & 63, w = tid >> 6;
  int wi = w >> 1, wj = w & 1;
  int q = lane >> 4, r = lane & 15;
  int srow = tid >> 2, scol = (tid & 3) * 8;

  const unsigned short* sP = s + (size_t)(i0 + srow) * 512 + scol;
  const unsigned short* WbP = Wb + (size_t)srow * 512 + scol;
  const unsigned short* WgP = Wgru + (size_t)srow * 384 + scol;

  // ---- phase B: 16 windows (BK=32) ----
  f32x4 accm[2][8];
#pragma unroll
  for (int a = 0; a < 2; a++)
#pragma unroll
    for (int b = 0; b < 8; b++) accm[a][b] = f32x4{0.f, 0.f, 0.f, 0.f};

  for (int ks = 0; ks < 16; ks++) {
    cp16(&stg[w * 512], sP + ks * 32);
#pragma unroll
    for (int c = 0; c < 4; c++)
      cp16(&stg[2048 + c * 2048 + w * 512], WbP + (size_t)(c * 64) * 512 + ks * 32);
    __syncthreads();
    bfrag af[2];
#pragma unroll
    for (int rt = 0; rt < 2; rt++)
      af[rt] = *(const bfrag*)&stg[(wi * 32 + rt * 16 + r) * 32 + q * 8];
#pragma unroll
    for (int ct = 0; ct < 8; ct++) {
      bfrag bfr = *(const bfrag*)&stg[2048 + (wj * 128 + ct * 16 + r) * 32 + q * 8];
#pragma unroll
      for (int rt = 0; rt < 2; rt++)
        accm[rt][ct] =
            __builtin_amdgcn_mfma_f32_16x16x32_bf16(af[rt], bfr, accm[rt][ct], 0, 0, 0);
    }
    __syncthreads();
  }

  // H fragments for phase C k=256..383 (registers; issued early)
  bfrag hfr[4][2];
#pragma unroll
  for (int kh = 0; kh < 4; kh++)
#pragma unroll
    for (int rt = 0; rt < 2; rt++)
      hfr[kh][rt] =
          *(const bfrag*)&Hc[(size_t)(i0 + wi * 32 + rt * 16 + r) * 128 + kh * 32 + q * 8];

  // ---- m epilogue: + cnt*b_msg, relu -> mT ----
#pragma unroll
  for (int ct = 0; ct < 8; ct++) {
    int j = wj * 128 + ct * 16 + r;
    float b0 = bmsg[j], b1 = bmsg[256 + j], b2 = bmsg[512 + j], b3 = bmsg[768 + j];
#pragma unroll
    for (int rt = 0; rt < 2; rt++) {
#pragma unroll
      for (int reg = 0; reg < 4; reg++) {
        int il = wi * 32 + rt * 16 + q * 4 + reg;
        float4 c4 = *(const float4*)&cnt[(size_t)(i0 + il) * 4];
        float v = accm[rt][ct][reg] + c4.x * b0 + c4.y * b1 + c4.z * b2 + c4.w * b3;
        v = v > 0.f ? v : 0.f;
        mT[il * 264 + j] = f2bf(v);
      }
    }
  }

  // ---- phase C: 2 jh x 12 windows ----
  for (int jh = 0; jh < 2; jh++) {
    f32x4 acc[2][8];
#pragma unroll
    for (int a = 0; a < 2; a++)
#pragma unroll
      for (int b = 0; b < 8; b++) acc[a][b] = f32x4{0.f, 0.f, 0.f, 0.f};

    for (int ks = 0; ks < 12; ks++) {
#pragma unroll
      for (int c = 0; c < 4; c++)
        cp16(&stg[2048 + c * 2048 + w * 512],
             WgP + (size_t)(jh * 256 + c * 64) * 384 + ks * 32);
      __syncthreads();  // publishes staging (and mT on first iteration)
      bfrag af[2];
#pragma unroll
      for (int rt = 0; rt < 2; rt++)
        af[rt] = (ks < 8)
                     ? *(const bfrag*)&mT[(wi * 32 + rt * 16 + r) * 264 + ks * 32 + q * 8]
                     : hfr[ks - 8][rt];
#pragma unroll
      for (int ct = 0; ct < 8; ct++) {
        bfrag bfr = *(const bfrag*)&stg[2048 + (wj * 128 + ct * 16 + r) * 32 + q * 8];
#pragma unroll
        for (int rt = 0; rt < 2; rt++)
          acc[rt][ct] =
              __builtin_amdgcn_mfma_f32_16x16x32_bf16(af[rt], bfr, acc[rt][ct], 0, 0, 0);
      }
      __syncthreads();
    }

    // GRU epilogue: cols are 4*d+g; quad transpose gives each lane its 4 gates
    int rr = r & 3;
    bool s1 = (lane & 1) != 0, s2 = (lane & 2) != 0;
#pragma unroll
    for (int ct = 0; ct < 8; ct++) {
      float bias = biasg[jh * 256 + wj * 128 + ct * 16 + r];
      int d = jh * 64 + wj * 32 + ct * 4 + (r >> 2);
#pragma unroll
      for (int rt = 0; rt < 2; rt++) {
        float v0 = acc[rt][ct][0] + bias;
        float v1 = acc[rt][ct][1] + bias;
        float v2 = acc[rt][ct][2] + bias;
        float v3 = acc[rt][ct][3] + bias;
        float t, rcv;
        t = s1 ? v0 : v1; rcv = __shfl_xor(t, 1);
        v0 = s1 ? rcv : v0; v1 = s1 ? v1 : rcv;
        t = s1 ? v2 : v3; rcv = __shfl_xor(t, 1);
        v2 = s1 ? rcv : v2; v3 = s1 ? v3 : rcv;
        t = s2 ? v0 : v2; rcv = __shfl_xor(t, 2);
        v0 = s2 ? rcv : v0; v2 = s2 ? v2 : rcv;
        t = s2 ? v1 : v3; rcv = __shfl_xor(t, 2);
        v1 = s2 ? rcv : v1; v3 = s2 ? v3 : rcv;
        int i = i0 + wi * 32 + rt * 16 + q * 4 + rr;
        size_t hoff = (size_t)i * 128 + d;
        float hold = bf2f(Hc[hoff]);
        float rg = sigm(v0), zg = sigm(v1);
        float ng = tanhf(v2 + rg * v3);
        Hn[hoff] = f2bf((1.f - zg) * ng + zg * hold);
      }
    }
  }
}

// ---------------- readout ----------------
__global__ __launch_bounds__(256) void gate_k(const unsigned short* __restrict__ H,
                                              const float* __restrict__ Wg,
                                              const float* __restrict__ bg,
                                              float* __restrict__ gate) {
  __shared__ float wg[128];
  if (threadIdx.x < 128) wg[threadIdx.x] = Wg[threadIdx.x];
  __syncthreads();
  int g = threadIdx.x >> 4, sub = threadIdx.x & 15;
  int n = blockIdx.x * 16 + g;
  const unsigned short* hr = H + (size_t)n * 128;
  float p = 0.f;
  for (int k = sub; k < 128; k += 16) p += bf2f(hr[k]) * wg[k];
  p += __shfl_xor(p, 1);
  p += __shfl_xor(p, 2);
  p += __shfl_xor(p, 4);
  p += __shfl_xor(p, 8);
  if (sub == 0) gate[n] = sigm(p + bg[0]);
}

// per-graph: gsum[g] = sum gate_n * h_n (fp32), sg[g] = sum gate_n
__global__ __launch_bounds__(256) void gsum_k(const unsigned short* __restrict__ H,
                                              const float* __restrict__ gate,
                                              const int* __restrict__ ptr,
                                              float* __restrict__ gsum,
                                              float* __restrict__ sg) {
  int g = blockIdx.x * 4 + (threadIdx.x >> 6);
  int lane = threadIdx.x & 63;
  int start = ptr[g], end = ptr[g + 1];
  float a0 = 0.f, a1 = 0.f, gs = 0.f;
  for (int n = start; n < end; n++) {
    float gt = gate[n];
    unsigned hv = *(const unsigned*)&H[(size_t)n * 128 + lane * 2];
    a0 += gt * bf2f((unsigned short)(hv & 0xffffu));
    a1 += gt * bf2f((unsigned short)(hv >> 16));
    gs += gt;
  }
  gsum[(size_t)g * 128 + lane * 2] = a0;
  gsum[(size_t)g * 128 + lane * 2 + 1] = a1;
  if (lane == 0) sg[g] = gs;
}

// z[j] = gsum[g] . WcT[:,j] + sg[g]*cvec[j] + bias[j]
__global__ __launch_bounds__(256) void zfinal_k(const float* __restrict__ gsum,
                                                const float* __restrict__ sg,
                                                const float* __restrict__ WcT,
                                                const float* __restrict__ cvec,
                                                const float* __restrict__ bloc,
                                                const float* __restrict__ blv,
                                                float* __restrict__ out) {
  __shared__ float gs[128];
  __shared__ float sgs;
  int g = blockIdx.x;
  int j = threadIdx.x;
  if (j < 128) gs[j] = gsum[(size_t)g * 128 + j];
  if (j == 0) sgs = sg[g];
  __syncthreads();
  float acc = (j < 128 ? bloc[j] : blv[j - 128]) + sgs * cvec[j];
  for (int d = 0; d < 128; d++) acc += gs[d] * WcT[d * 256 + j];
  size_t o = (j < 128) ? ((size_t)g * 128 + j)
                       : ((size_t)GG * 128 + (size_t)g * 128 + (j - 128));
  out[o] = acc;
}

extern "C" void kernel_launch(void* const* d_in, const int* in_sizes, int n_in,
                              void* d_out, int out_size, void* d_ws, size_t ws_size,
                              hipStream_t stream) {
  const int* node_types = (const int*)d_in[0];
  const int* esrc = (const int*)d_in[1];
  const int* edst = (const int*)d_in[2];
  const int* etype = (const int*)d_in[3];
  const int* ptr = (const int*)d_in[4];
  const float* emb = (const float*)d_in[5];
  const float* Wmsg = (const float*)d_in[6];
  const float* bmsg = (const float*)d_in[7];
  const float* Wih = (const float*)d_in[8];
  const float* Whh = (const float*)d_in[9];
  const float* bih = (const float*)d_in[10];
  const float* bhh = (const float*)d_in[11];
  const float* Wg = (const float*)d_in[12];
  const float* bg = (const float*)d_in[13];
  const float* Wn2g = (const float*)d_in[14];
  const float* bn2g = (const float*)d_in[15];
  const float* Wloc = (const float*)d_in[16];
  const float* bloc = (const float*)d_in[17];
  const float* Wlv = (const float*)d_in[18];
  const float* blv = (const float*)d_in[19];
  float* out = (float*)d_out;

  char* ws = (char*)d_ws;
  size_t off = 0;
  unsigned short* s = (unsigned short*)(ws);  // N x 512 bf16
  off += (size_t)NN * 512 * 2;
  unsigned short* H0 = (unsigned short*)(ws + off);  // N x 128 bf16
  off += (size_t)NN * 128 * 2;
  unsigned short* H1 = (unsigned short*)(ws + off);
  off += (size_t)NN * 128 * 2;
  float* cnt = (float*)(ws + off);
  off += (size_t)NN * 4 * 4;
  int* cnti = (int*)(ws + off);
  off += (size_t)NN * 4 * 4;
  int* rowptr = (int*)(ws + off);
  off += (size_t)(NN + 64) * 4;
  int* cursor = (int*)(ws + off);
  off += (size_t)NN * 4;
  unsigned* epack = (unsigned*)(ws + off);
  off += (size_t)EE * 4;
  float* gate = (float*)(ws + off);
  off += (size_t)NN * 4;
  float* gsum = (float*)(ws + off);
  off += (size_t)GG * 128 * 4;
  float* sg = (float*)(ws + off);
  off += (size_t)GG * 4;
  float* WcT = (float*)(ws + off);
  off += 128 * 256 * 4;
  float* cvec = (float*)(ws + off);
  off += 256 * 4;
  unsigned short* Wb = (unsigned short*)(ws + off);
  off += 256 * 512 * 2;
  unsigned short* Wgru = (unsigned short*)(ws + off);
  off += 512 * 384 * 2;
  float* biasg = (float*)(ws + off);
  off += 512 * 4;
  // total ~213 MB < 256 MiB ws

  hipMemsetAsync(cnti, 0, (size_t)NN * 16, stream);
  prep_wb<<<512, 256, 0, stream>>>(Wmsg, Wb);
  prep_wgru<<<768, 256, 0, stream>>>(Wih, Whh, Wgru);
  prep_bias<<<2, 256, 0, stream>>>(bih, bhh, biasg);
  compose_k<<<128, 256, 0, stream>>>(Wloc, Wlv, Wn2g, WcT);
  cvec_k<<<1, 256, 0, stream>>>(Wloc, Wlv, bn2g, cvec);
  init_h<<<NN * 128 / 256, 256, 0, stream>>>(node_types, emb, H0);
  cnt4_k<<<EE / 256, 256, 0, stream>>>(edst, etype, cnti);
  scan_k<<<1, 1024, 0, stream>>>(cnti, rowptr, cursor);
  cvt_k<<<NN * 4 / 256, 256, 0, stream>>>(cnti, cnt);
  fill_k<<<EE / 256, 256, 0, stream>>>(esrc, edst, etype, cursor, epack);

  unsigned short* Hc = H0;
  unsigned short* Hn = H1;
  for (int p = 0; p < NPASS; p++) {
    agg_k<<<NN / 4, 256, 0, stream>>>(rowptr, epack, Hc, s);
    mgru_k<<<NN / 64, 256, 0, stream>>>(s, cnt, Hc, Hn, Wb, Wgru, bmsg, biasg);
    unsigned short* tmp = Hc; Hc = Hn; Hn = tmp;
  }

  gate_k<<<NN / 16, 256, 0, stream>>>(Hc, Wg, bg, gate);
  gsum_k<<<GG / 4, 256, 0, stream>>>(Hc, gate, ptr, gsum, sg);
  zfinal_k<<<GG, 256, 0, stream>>>(gsum, sg, WcT, cvec, bloc, blv, out);
}

// Round 12
// 1478.378 us; speedup vs baseline: 1.0417x; 1.0417x over previous
//
#include <hip/hip_runtime.h>
#include <cstdint>
#include <cstddef>

#define NN 131072
#define EE 524288
#define GG 4096
#define NPASS 4

typedef __attribute__((ext_vector_type(4))) float f32x4;
typedef __attribute__((ext_vector_type(8))) short bfrag;

__device__ __forceinline__ unsigned short f2bf(float f) {
  union { float f; unsigned u; } v; v.f = f;
  unsigned r = v.u + 0x7fffu + ((v.u >> 16) & 1u);
  return (unsigned short)(r >> 16);
}
__device__ __forceinline__ float bf2f(unsigned short h) {
  union { unsigned u; float f; } v; v.u = ((unsigned)h) << 16;
  return v.f;
}
__device__ __forceinline__ unsigned pack2(float x, float y) {
  return (unsigned)f2bf(x) | ((unsigned)f2bf(y) << 16);
}
__device__ __forceinline__ float sigm(float x) { return 1.f / (1.f + __expf(-x)); }

// async global->LDS 16B: LDS dest is wave-uniform base + lane*16
__device__ __forceinline__ void cp16(unsigned short* l, const unsigned short* g) {
  __builtin_amdgcn_global_load_lds(
      (const __attribute__((address_space(1))) unsigned int*)g,
      (__attribute__((address_space(3))) unsigned int*)l, 16, 0, 0);
}

// ---------------- weight prep ----------------
__global__ void prep_wb(const float* __restrict__ Wmsg, unsigned short* __restrict__ Wb) {
  int idx = blockIdx.x * 256 + threadIdx.x;  // 256*512
  if (idx >= 256 * 512) return;
  int m = idx >> 9, k = idx & 511;
  int t = k >> 7, d = k & 127;
  Wb[idx] = f2bf(Wmsg[((size_t)t * 256 + m) * 128 + d]);
}

// Wgru rows interleaved by gate: out-col = 4*d + g, g in {r,z,n,hn}
__global__ void prep_wgru(const float* __restrict__ Wih, const float* __restrict__ Whh,
                          unsigned short* __restrict__ Wgru) {
  int idx = blockIdx.x * 256 + threadIdx.x;  // 512*384
  if (idx >= 512 * 384) return;
  int j = idx / 384, kk = idx % 384;
  float v;
  if (kk < 256) v = (j < 384) ? Wih[j * 256 + kk] : 0.f;
  else          v = (j < 256) ? Whh[j * 128 + (kk - 256)]
                   : ((j >= 384) ? Whh[(j - 128) * 128 + (kk - 256)] : 0.f);
  int g = (j < 128) ? 0 : (j < 256) ? 1 : (j < 384) ? 2 : 3;
  int d = j & 127;
  Wgru[(size_t)(4 * d + g) * 384 + kk] = f2bf(v);
}

__global__ void prep_bias(const float* __restrict__ bih, const float* __restrict__ bhh,
                          float* __restrict__ biasg) {
  int j = blockIdx.x * 256 + threadIdx.x;
  if (j >= 512) return;
  float v;
  if (j < 256) v = bih[j] + bhh[j];
  else if (j < 384) v = bih[j];
  else v = bhh[j - 128];
  int g = (j < 128) ? 0 : (j < 256) ? 1 : (j < 384) ? 2 : 3;
  int d = j & 127;
  biasg[4 * d + g] = v;
}

// WcT[d*256 + j] = sum_k Wx[j][k] * Wn2g[k*128+d], Wx = [Wloc; Wlv] (fp32)
__global__ void compose_k(const float* __restrict__ Wloc, const float* __restrict__ Wlv,
                          const float* __restrict__ Wn2g, float* __restrict__ WcT) {
  int b = blockIdx.x;  // 128 blocks
  int jl = threadIdx.x >> 7, d = threadIdx.x & 127;
  int j = b * 2 + jl;
  const float* wx = (j < 128) ? Wloc + (size_t)j * 512 : Wlv + (size_t)(j - 128) * 512;
  float acc = 0.f;
  for (int k = 0; k < 512; k++) acc += wx[k] * Wn2g[k * 128 + d];
  WcT[d * 256 + j] = acc;
}

__global__ void cvec_k(const float* __restrict__ Wloc, const float* __restrict__ Wlv,
                       const float* __restrict__ bn2g, float* __restrict__ cvec) {
  int j = threadIdx.x;  // 256
  const float* wx = (j < 128) ? Wloc + (size_t)j * 512 : Wlv + (size_t)(j - 128) * 512;
  float a = 0.f;
  for (int k = 0; k < 512; k++) a += wx[k] * bn2g[k];
  cvec[j] = a;
}

// ---------------- init ----------------
__global__ void init_h(const int* __restrict__ nt, const float* __restrict__ emb,
                       unsigned short* __restrict__ H) {
  size_t idx = (size_t)blockIdx.x * 256 + threadIdx.x;  // N*128
  int n = (int)(idx >> 7), d = (int)(idx & 127);
  H[idx] = f2bf(emb[(size_t)nt[n] * 128 + d]);
}

// ---------------- CSR build (once per call) ----------------
__global__ void cnt4_k(const int* __restrict__ edst, const int* __restrict__ etype,
                       int* __restrict__ cnti) {
  int e = blockIdx.x * 256 + threadIdx.x;
  if (e >= EE) return;
  atomicAdd(&cnti[edst[e] * 4 + etype[e]], 1);
}

__global__ void cvt_k(const int* __restrict__ cnti, float* __restrict__ cnt) {
  int i = blockIdx.x * 256 + threadIdx.x;  // 4N
  if (i >= 4 * NN) return;
  cnt[i] = (float)cnti[i];
}

__global__ __launch_bounds__(1024) void scan_k(const int* __restrict__ cnti,
                                               int* __restrict__ rowptr,
                                               int* __restrict__ cursor) {
  __shared__ int part[1024];
  int t = threadIdx.x;
  int base = t * 128;
  int s = 0;
  for (int i = 0; i < 128; i++) {
    const int* c4 = &cnti[(base + i) * 4];
    s += c4[0] + c4[1] + c4[2] + c4[3];
  }
  part[t] = s;
  __syncthreads();
  for (int off = 1; off < 1024; off <<= 1) {
    int v = (t >= off) ? part[t - off] : 0;
    __syncthreads();
    part[t] += v;
    __syncthreads();
  }
  int run = part[t] - s;  // exclusive prefix
  for (int i = 0; i < 128; i++) {
    rowptr[base + i] = run;
    cursor[base + i] = run;
    const int* c4 = &cnti[(base + i) * 4];
    run += c4[0] + c4[1] + c4[2] + c4[3];
  }
  if (t == 1023) rowptr[NN] = run;
}

__global__ void fill_k(const int* __restrict__ esrc, const int* __restrict__ edst,
                       const int* __restrict__ etype, int* __restrict__ cursor,
                       unsigned* __restrict__ epack) {
  int e = blockIdx.x * 256 + threadIdx.x;
  if (e >= EE) return;
  int pos = atomicAdd(&cursor[edst[e]], 1);
  epack[pos] = ((unsigned)etype[e] << 17) | (unsigned)esrc[e];
}

// ---------------- per-pass aggregation: s[n, t*128+d] = sum h[src] (bf16 out) ----------------
__global__ __launch_bounds__(256) void agg_k(const int* __restrict__ rowptr,
                                             const unsigned* __restrict__ epack,
                                             const unsigned short* __restrict__ H,
                                             unsigned short* __restrict__ s) {
  int n = blockIdx.x * 4 + (threadIdx.x >> 6);
  int lane = threadIdx.x & 63;
  int beg = rowptr[n], end = rowptr[n + 1];
  const unsigned short* hbase = H + lane * 2;
  float a0 = 0.f, a1 = 0.f, b0 = 0.f, b1 = 0.f;
  float c0 = 0.f, c1 = 0.f, d0 = 0.f, d1 = 0.f;
  for (int base = beg; base < end; base += 64) {
    int cnt = end - base;
    if (cnt > 64) cnt = 64;
    int mye = base + lane;
    unsigned ep = (mye < end) ? epack[mye] : 0u;  // coalesced pre-load
    for (int j = 0; j < cnt; j++) {
      unsigned p = (unsigned)__shfl((int)ep, j);  // wave-uniform edge
      int src = (int)(p & 0x1FFFFu);
      int t = (int)(p >> 17);
      unsigned hv = *(const unsigned*)&hbase[(size_t)src * 128];
      float v0 = bf2f((unsigned short)(hv & 0xffffu));
      float v1 = bf2f((unsigned short)(hv >> 16));
      if (t == 0)      { a0 += v0; a1 += v1; }
      else if (t == 1) { b0 += v0; b1 += v1; }
      else if (t == 2) { c0 += v0; c1 += v1; }
      else             { d0 += v0; d1 += v1; }
    }
  }
  unsigned short* srow = s + (size_t)n * 512;
  *(unsigned*)&srow[0 * 128 + lane * 2] = pack2(a0, a1);
  *(unsigned*)&srow[1 * 128 + lane * 2] = pack2(b0, b1);
  *(unsigned*)&srow[2 * 128 + lane * 2] = pack2(c0, c1);
  *(unsigned*)&srow[3 * 128 + lane * 2] = pack2(d0, d1);
}

// ---------------- fused m+GRU GEMM: 128 rows/block, 8 waves, dbuf staging ----------------
// Wave tile 32x128: wi = w>>1 (row group), wj = w&1 (col half).
// phase B: m = relu(s @ Wb^T + cnt*b_msg) -> LDS mT (128 x stride 264)
// phase C: GRU GEMM [m | H] @ Wgru^T (cols gate-interleaved 4*d+g), 2 jh halves,
//          quad-transpose GRU epilogue -> Hn.
// LDS: mT 67584 + stg 2x24576 = 116736 B -> 1 block/CU, 8 waves.
// Weight staging per row is HALF of the 64-row version (same 16KB W tile feeds 128 rows).
__global__ __launch_bounds__(512, 2) void mgru_k(
    const unsigned short* __restrict__ s, const float* __restrict__ cnt,
    const unsigned short* __restrict__ Hc, unsigned short* __restrict__ Hn,
    const unsigned short* __restrict__ Wb, const unsigned short* __restrict__ Wgru,
    const float* __restrict__ bmsg, const float* __restrict__ biasg) {
  __shared__ __align__(16) unsigned short mT[128 * 264];   // 67584 B
  __shared__ __align__(16) unsigned short stg[2][12288];   // shorts: As[0,4096) Ws[4096,12288)
  int i0 = blockIdx.x * 128;
  int tid = threadIdx.x, lane = tid & 63, w = tid >> 6;
  int wi = w >> 1, wj = w & 1;
  int q = lane >> 4, r = lane & 15;
  int trow = tid >> 2;         // 0..127
  int tcol = (tid & 3) * 8;    // 0,8,16,24

  const unsigned short* sP = s + (size_t)(i0 + trow) * 512 + tcol;
  const unsigned short* WbP = Wb + (size_t)trow * 512 + tcol;
  const unsigned short* WgP = Wgru + (size_t)trow * 384 + tcol;

  // ---- phase B: 16 windows (BK=32), double-buffered ----
  f32x4 accm[2][8];
#pragma unroll
  for (int a = 0; a < 2; a++)
#pragma unroll
    for (int b = 0; b < 8; b++) accm[a][b] = f32x4{0.f, 0.f, 0.f, 0.f};

  // pre-stage ks=0
  cp16(&stg[0][w * 512], sP);
  cp16(&stg[0][4096 + w * 512], WbP);                         // W rows 0-127
  cp16(&stg[0][8192 + w * 512], WbP + (size_t)128 * 512);     // W rows 128-255
  __syncthreads();

  for (int ks = 0; ks < 16; ks++) {
    int b = ks & 1;
    if (ks < 15) {
      int nb = b ^ 1;
      cp16(&stg[nb][w * 512], sP + (ks + 1) * 32);
      cp16(&stg[nb][4096 + w * 512], WbP + (ks + 1) * 32);
      cp16(&stg[nb][8192 + w * 512], WbP + (size_t)128 * 512 + (ks + 1) * 32);
    }
    bfrag af[2];
#pragma unroll
    for (int rt = 0; rt < 2; rt++)
      af[rt] = *(const bfrag*)&stg[b][(wi * 32 + rt * 16 + r) * 32 + q * 8];
#pragma unroll
    for (int ct = 0; ct < 8; ct++) {
      bfrag bfr = *(const bfrag*)&stg[b][4096 + (wj * 128 + ct * 16 + r) * 32 + q * 8];
#pragma unroll
      for (int rt = 0; rt < 2; rt++)
        accm[rt][ct] =
            __builtin_amdgcn_mfma_f32_16x16x32_bf16(af[rt], bfr, accm[rt][ct], 0, 0, 0);
    }
    __syncthreads();
  }

  // H fragments for phase C k=256..383 (registers; issued early)
  bfrag hfr[4][2];
#pragma unroll
  for (int kh = 0; kh < 4; kh++)
#pragma unroll
    for (int rt = 0; rt < 2; rt++)
      hfr[kh][rt] =
          *(const bfrag*)&Hc[(size_t)(i0 + wi * 32 + rt * 16 + r) * 128 + kh * 32 + q * 8];

  // ---- m epilogue: + cnt*b_msg, relu -> mT ----
#pragma unroll
  for (int ct = 0; ct < 8; ct++) {
    int j = wj * 128 + ct * 16 + r;
    float b0 = bmsg[j], b1 = bmsg[256 + j], b2 = bmsg[512 + j], b3 = bmsg[768 + j];
#pragma unroll
    for (int rt = 0; rt < 2; rt++) {
#pragma unroll
      for (int reg = 0; reg < 4; reg++) {
        int il = wi * 32 + rt * 16 + q * 4 + reg;
        float4 c4 = *(const float4*)&cnt[(size_t)(i0 + il) * 4];
        float v = accm[rt][ct][reg] + c4.x * b0 + c4.y * b1 + c4.z * b2 + c4.w * b3;
        v = v > 0.f ? v : 0.f;
        mT[il * 264 + j] = f2bf(v);
      }
    }
  }
  // pre-stage phase-C window v=0 (jh=0, ks=0) into buffer 0
  cp16(&stg[0][4096 + w * 512], WgP);
  cp16(&stg[0][8192 + w * 512], WgP + (size_t)128 * 384);
  __syncthreads();  // publishes mT + drains v0 staging

  // ---- phase C: 24 windows (2 jh x 12 ks), double-buffered ----
  for (int jh = 0; jh < 2; jh++) {
    f32x4 acc[2][8];
#pragma unroll
    for (int a = 0; a < 2; a++)
#pragma unroll
      for (int b = 0; b < 8; b++) acc[a][b] = f32x4{0.f, 0.f, 0.f, 0.f};

    for (int ks = 0; ks < 12; ks++) {
      int v = jh * 12 + ks;
      int b = v & 1;
      if (v < 23) {
        int nb = b ^ 1;
        int nv = v + 1;
        int njh = nv >= 12 ? 1 : 0;
        int nks = nv - njh * 12;
        cp16(&stg[nb][4096 + w * 512],
             WgP + (size_t)(njh * 256) * 384 + nks * 32);
        cp16(&stg[nb][8192 + w * 512],
             WgP + (size_t)(njh * 256 + 128) * 384 + nks * 32);
      }
      bfrag af[2];
#pragma unroll
      for (int rt = 0; rt < 2; rt++)
        af[rt] = (ks < 8)
                     ? *(const bfrag*)&mT[(wi * 32 + rt * 16 + r) * 264 + ks * 32 + q * 8]
                     : hfr[ks - 8][rt];
#pragma unroll
      for (int ct = 0; ct < 8; ct++) {
        bfrag bfr = *(const bfrag*)&stg[b][4096 + (wj * 128 + ct * 16 + r) * 32 + q * 8];
#pragma unroll
        for (int rt = 0; rt < 2; rt++)
          acc[rt][ct] =
              __builtin_amdgcn_mfma_f32_16x16x32_bf16(af[rt], bfr, acc[rt][ct], 0, 0, 0);
      }
      __syncthreads();
    }

    // GRU epilogue: cols are 4*d+g; quad transpose gives each lane its 4 gates
    int rr = r & 3;
    bool s1 = (lane & 1) != 0, s2 = (lane & 2) != 0;
#pragma unroll
    for (int ct = 0; ct < 8; ct++) {
      float bias = biasg[jh * 256 + wj * 128 + ct * 16 + r];
      int d = jh * 64 + wj * 32 + ct * 4 + (r >> 2);
#pragma unroll
      for (int rt = 0; rt < 2; rt++) {
        float v0 = acc[rt][ct][0] + bias;
        float v1 = acc[rt][ct][1] + bias;
        float v2 = acc[rt][ct][2] + bias;
        float v3 = acc[rt][ct][3] + bias;
        float t, rcv;
        t = s1 ? v0 : v1; rcv = __shfl_xor(t, 1);
        v0 = s1 ? rcv : v0; v1 = s1 ? v1 : rcv;
        t = s1 ? v2 : v3; rcv = __shfl_xor(t, 1);
        v2 = s1 ? rcv : v2; v3 = s1 ? v3 : rcv;
        t = s2 ? v0 : v2; rcv = __shfl_xor(t, 2);
        v0 = s2 ? rcv : v0; v2 = s2 ? v2 : rcv;
        t = s2 ? v1 : v3; rcv = __shfl_xor(t, 2);
        v1 = s2 ? rcv : v1; v3 = s2 ? v3 : rcv;
        int i = i0 + wi * 32 + rt * 16 + q * 4 + rr;
        size_t hoff = (size_t)i * 128 + d;
        float hold = bf2f(Hc[hoff]);
        float rg = sigm(v0), zg = sigm(v1);
        float ng = tanhf(v2 + rg * v3);
        Hn[hoff] = f2bf((1.f - zg) * ng + zg * hold);
      }
    }
  }
}

// ---------------- readout ----------------
__global__ __launch_bounds__(256) void gate_k(const unsigned short* __restrict__ H,
                                              const float* __restrict__ Wg,
                                              const float* __restrict__ bg,
                                              float* __restrict__ gate) {
  __shared__ float wg[128];
  if (threadIdx.x < 128) wg[threadIdx.x] = Wg[threadIdx.x];
  __syncthreads();
  int g = threadIdx.x >> 4, sub = threadIdx.x & 15;
  int n = blockIdx.x * 16 + g;
  const unsigned short* hr = H + (size_t)n * 128;
  float p = 0.f;
  for (int k = sub; k < 128; k += 16) p += bf2f(hr[k]) * wg[k];
  p += __shfl_xor(p, 1);
  p += __shfl_xor(p, 2);
  p += __shfl_xor(p, 4);
  p += __shfl_xor(p, 8);
  if (sub == 0) gate[n] = sigm(p + bg[0]);
}

// per-graph: gsum[g] = sum gate_n * h_n (fp32), sg[g] = sum gate_n
__global__ __launch_bounds__(256) void gsum_k(const unsigned short* __restrict__ H,
                                              const float* __restrict__ gate,
                                              const int* __restrict__ ptr,
                                              float* __restrict__ gsum,
                                              float* __restrict__ sg) {
  int g = blockIdx.x * 4 + (threadIdx.x >> 6);
  int lane = threadIdx.x & 63;
  int start = ptr[g], end = ptr[g + 1];
  float a0 = 0.f, a1 = 0.f, gs = 0.f;
  for (int n = start; n < end; n++) {
    float gt = gate[n];
    unsigned hv = *(const unsigned*)&H[(size_t)n * 128 + lane * 2];
    a0 += gt * bf2f((unsigned short)(hv & 0xffffu));
    a1 += gt * bf2f((unsigned short)(hv >> 16));
    gs += gt;
  }
  gsum[(size_t)g * 128 + lane * 2] = a0;
  gsum[(size_t)g * 128 + lane * 2 + 1] = a1;
  if (lane == 0) sg[g] = gs;
}

// z[j] = gsum[g] . WcT[:,j] + sg[g]*cvec[j] + bias[j]
__global__ __launch_bounds__(256) void zfinal_k(const float* __restrict__ gsum,
                                                const float* __restrict__ sg,
                                                const float* __restrict__ WcT,
                                                const float* __restrict__ cvec,
                                                const float* __restrict__ bloc,
                                                const float* __restrict__ blv,
                                                float* __restrict__ out) {
  __shared__ float gs[128];
  __shared__ float sgs;
  int g = blockIdx.x;
  int j = threadIdx.x;
  if (j < 128) gs[j] = gsum[(size_t)g * 128 + j];
  if (j == 0) sgs = sg[g];
  __syncthreads();
  float acc = (j < 128 ? bloc[j] : blv[j - 128]) + sgs * cvec[j];
  for (int d = 0; d < 128; d++) acc += gs[d] * WcT[d * 256 + j];
  size_t o = (j < 128) ? ((size_t)g * 128 + j)
                       : ((size_t)GG * 128 + (size_t)g * 128 + (j - 128));
  out[o] = acc;
}

extern "C" void kernel_launch(void* const* d_in, const int* in_sizes, int n_in,
                              void* d_out, int out_size, void* d_ws, size_t ws_size,
                              hipStream_t stream) {
  const int* node_types = (const int*)d_in[0];
  const int* esrc = (const int*)d_in[1];
  const int* edst = (const int*)d_in[2];
  const int* etype = (const int*)d_in[3];
  const int* ptr = (const int*)d_in[4];
  const float* emb = (const float*)d_in[5];
  const float* Wmsg = (const float*)d_in[6];
  const float* bmsg = (const float*)d_in[7];
  const float* Wih = (const float*)d_in[8];
  const float* Whh = (const float*)d_in[9];
  const float* bih = (const float*)d_in[10];
  const float* bhh = (const float*)d_in[11];
  const float* Wg = (const float*)d_in[12];
  const float* bg = (const float*)d_in[13];
  const float* Wn2g = (const float*)d_in[14];
  const float* bn2g = (const float*)d_in[15];
  const float* Wloc = (const float*)d_in[16];
  const float* bloc = (const float*)d_in[17];
  const float* Wlv = (const float*)d_in[18];
  const float* blv = (const float*)d_in[19];
  float* out = (float*)d_out;

  char* ws = (char*)d_ws;
  size_t off = 0;
  unsigned short* s = (unsigned short*)(ws);  // N x 512 bf16
  off += (size_t)NN * 512 * 2;
  unsigned short* H0 = (unsigned short*)(ws + off);  // N x 128 bf16
  off += (size_t)NN * 128 * 2;
  unsigned short* H1 = (unsigned short*)(ws + off);
  off += (size_t)NN * 128 * 2;
  float* cnt = (float*)(ws + off);
  off += (size_t)NN * 4 * 4;
  int* cnti = (int*)(ws + off);
  off += (size_t)NN * 4 * 4;
  int* rowptr = (int*)(ws + off);
  off += (size_t)(NN + 64) * 4;
  int* cursor = (int*)(ws + off);
  off += (size_t)NN * 4;
  unsigned* epack = (unsigned*)(ws + off);
  off += (size_t)EE * 4;
  float* gate = (float*)(ws + off);
  off += (size_t)NN * 4;
  float* gsum = (float*)(ws + off);
  off += (size_t)GG * 128 * 4;
  float* sg = (float*)(ws + off);
  off += (size_t)GG * 4;
  float* WcT = (float*)(ws + off);
  off += 128 * 256 * 4;
  float* cvec = (float*)(ws + off);
  off += 256 * 4;
  unsigned short* Wb = (unsigned short*)(ws + off);
  off += 256 * 512 * 2;
  unsigned short* Wgru = (unsigned short*)(ws + off);
  off += 512 * 384 * 2;
  float* biasg = (float*)(ws + off);
  off += 512 * 4;
  // total ~213 MB < 256 MiB ws

  hipMemsetAsync(cnti, 0, (size_t)NN * 16, stream);
  prep_wb<<<512, 256, 0, stream>>>(Wmsg, Wb);
  prep_wgru<<<768, 256, 0, stream>>>(Wih, Whh, Wgru);
  prep_bias<<<2, 256, 0, stream>>>(bih, bhh, biasg);
  compose_k<<<128, 256, 0, stream>>>(Wloc, Wlv, Wn2g, WcT);
  cvec_k<<<1, 256, 0, stream>>>(Wloc, Wlv, bn2g, cvec);
  init_h<<<NN * 128 / 256, 256, 0, stream>>>(node_types, emb, H0);
  cnt4_k<<<EE / 256, 256, 0, stream>>>(edst, etype, cnti);
  scan_k<<<1, 1024, 0, stream>>>(cnti, rowptr, cursor);
  cvt_k<<<NN * 4 / 256, 256, 0, stream>>>(cnti, cnt);
  fill_k<<<EE / 256, 256, 0, stream>>>(esrc, edst, etype, cursor, epack);

  unsigned short* Hc = H0;
  unsigned short* Hn = H1;
  for (int p = 0; p < NPASS; p++) {
    agg_k<<<NN / 4, 256, 0, stream>>>(rowptr, epack, Hc, s);
    mgru_k<<<NN / 128, 512, 0, stream>>>(s, cnt, Hc, Hn, Wb, Wgru, bmsg, biasg);
    unsigned short* tmp = Hc; Hc = Hn; Hn = tmp;
  }

  gate_k<<<NN / 16, 256, 0, stream>>>(Hc, Wg, bg, gate);
  gsum_k<<<GG / 4, 256, 0, stream>>>(Hc, gate, ptr, gsum, sg);
  zfinal_k<<<GG, 256, 0, stream>>>(gsum, sg, WcT, cvec, bloc, blv, out);
}

// Round 13
// 1337.997 us; speedup vs baseline: 1.1510x; 1.1049x over previous
//
#include <hip/hip_runtime.h>
#include <cstdint>
#include <cstddef>

#define NN 131072
#define EE 524288
#define GG 4096
#define NPASS 4

typedef __attribute__((ext_vector_type(4))) float f32x4;
typedef __attribute__((ext_vector_type(8))) short bfrag;

__device__ __forceinline__ unsigned short f2bf(float f) {
  union { float f; unsigned u; } v; v.f = f;
  unsigned r = v.u + 0x7fffu + ((v.u >> 16) & 1u);
  return (unsigned short)(r >> 16);
}
__device__ __forceinline__ float bf2f(unsigned short h) {
  union { unsigned u; float f; } v; v.u = ((unsigned)h) << 16;
  return v.f;
}
__device__ __forceinline__ unsigned pack2(float x, float y) {
  return (unsigned)f2bf(x) | ((unsigned)f2bf(y) << 16);
}
__device__ __forceinline__ float sigm(float x) { return 1.f / (1.f + __expf(-x)); }

// async global->LDS 16B: LDS dest is wave-uniform base + lane*16
__device__ __forceinline__ void cp16(unsigned short* l, const unsigned short* g) {
  __builtin_amdgcn_global_load_lds(
      (const __attribute__((address_space(1))) unsigned int*)g,
      (__attribute__((address_space(3))) unsigned int*)l, 16, 0, 0);
}

// ---------------- weight prep ----------------
__global__ void prep_wb(const float* __restrict__ Wmsg, unsigned short* __restrict__ Wb) {
  int idx = blockIdx.x * 256 + threadIdx.x;  // 256*512
  if (idx >= 256 * 512) return;
  int m = idx >> 9, k = idx & 511;
  int t = k >> 7, d = k & 127;
  Wb[idx] = f2bf(Wmsg[((size_t)t * 256 + m) * 128 + d]);
}

// Wgru rows interleaved by gate: out-col = 4*d + g, g in {r,z,n,hn}
__global__ void prep_wgru(const float* __restrict__ Wih, const float* __restrict__ Whh,
                          unsigned short* __restrict__ Wgru) {
  int idx = blockIdx.x * 256 + threadIdx.x;  // 512*384
  if (idx >= 512 * 384) return;
  int j = idx / 384, kk = idx % 384;
  float v;
  if (kk < 256) v = (j < 384) ? Wih[j * 256 + kk] : 0.f;
  else          v = (j < 256) ? Whh[j * 128 + (kk - 256)]
                   : ((j >= 384) ? Whh[(j - 128) * 128 + (kk - 256)] : 0.f);
  int g = (j < 128) ? 0 : (j < 256) ? 1 : (j < 384) ? 2 : 3;
  int d = j & 127;
  Wgru[(size_t)(4 * d + g) * 384 + kk] = f2bf(v);
}

__global__ void prep_bias(const float* __restrict__ bih, const float* __restrict__ bhh,
                          float* __restrict__ biasg) {
  int j = blockIdx.x * 256 + threadIdx.x;
  if (j >= 512) return;
  float v;
  if (j < 256) v = bih[j] + bhh[j];
  else if (j < 384) v = bih[j];
  else v = bhh[j - 128];
  int g = (j < 128) ? 0 : (j < 256) ? 1 : (j < 384) ? 2 : 3;
  int d = j & 127;
  biasg[4 * d + g] = v;
}

// WcT[d*256 + j] = sum_k Wx[j][k] * Wn2g[k*128+d], Wx = [Wloc; Wlv] (fp32)
__global__ void compose_k(const float* __restrict__ Wloc, const float* __restrict__ Wlv,
                          const float* __restrict__ Wn2g, float* __restrict__ WcT) {
  int b = blockIdx.x;  // 128 blocks
  int jl = threadIdx.x >> 7, d = threadIdx.x & 127;
  int j = b * 2 + jl;
  const float* wx = (j < 128) ? Wloc + (size_t)j * 512 : Wlv + (size_t)(j - 128) * 512;
  float acc = 0.f;
  for (int k = 0; k < 512; k++) acc += wx[k] * Wn2g[k * 128 + d];
  WcT[d * 256 + j] = acc;
}

__global__ void cvec_k(const float* __restrict__ Wloc, const float* __restrict__ Wlv,
                       const float* __restrict__ bn2g, float* __restrict__ cvec) {
  int j = threadIdx.x;  // 256
  const float* wx = (j < 128) ? Wloc + (size_t)j * 512 : Wlv + (size_t)(j - 128) * 512;
  float a = 0.f;
  for (int k = 0; k < 512; k++) a += wx[k] * bn2g[k];
  cvec[j] = a;
}

// ---------------- init ----------------
__global__ void init_h(const int* __restrict__ nt, const float* __restrict__ emb,
                       unsigned short* __restrict__ H) {
  size_t idx = (size_t)blockIdx.x * 256 + threadIdx.x;  // N*128
  int n = (int)(idx >> 7), d = (int)(idx & 127);
  H[idx] = f2bf(emb[(size_t)nt[n] * 128 + d]);
}

// ---------------- CSR build (once per call) ----------------
__global__ void cnt4_k(const int* __restrict__ edst, const int* __restrict__ etype,
                       int* __restrict__ cnti) {
  int e = blockIdx.x * 256 + threadIdx.x;
  if (e >= EE) return;
  atomicAdd(&cnti[edst[e] * 4 + etype[e]], 1);
}

// deg[n] = sum_t cnti[n*4+t]; cnt (float) copy
__global__ void degsum_k(const int* __restrict__ cnti, int* __restrict__ deg,
                         float* __restrict__ cnt) {
  int n = blockIdx.x * 256 + threadIdx.x;
  if (n >= NN) return;
  int4 c4 = *(const int4*)&cnti[n * 4];
  deg[n] = c4.x + c4.y + c4.z + c4.w;
  float4 f4 = make_float4((float)c4.x, (float)c4.y, (float)c4.z, (float)c4.w);
  *(float4*)&cnt[n * 4] = f4;
}

__global__ __launch_bounds__(1024) void scan_k(const int* __restrict__ deg,
                                               int* __restrict__ rowptr,
                                               int* __restrict__ cursor) {
  __shared__ int part[1024];
  int t = threadIdx.x;
  int base = t * 128;
  int s = 0;
  for (int i = 0; i < 128; i++) s += deg[base + i];
  part[t] = s;
  __syncthreads();
  for (int off = 1; off < 1024; off <<= 1) {
    int v = (t >= off) ? part[t - off] : 0;
    __syncthreads();
    part[t] += v;
    __syncthreads();
  }
  int run = part[t] - s;  // exclusive prefix
  for (int i = 0; i < 128; i++) {
    rowptr[base + i] = run;
    cursor[base + i] = run;
    run += deg[base + i];
  }
  if (t == 1023) rowptr[NN] = run;
}

__global__ void fill_k(const int* __restrict__ esrc, const int* __restrict__ edst,
                       const int* __restrict__ etype, int* __restrict__ cursor,
                       unsigned* __restrict__ epack) {
  int e = blockIdx.x * 256 + threadIdx.x;
  if (e >= EE) return;
  int pos = atomicAdd(&cursor[edst[e]], 1);
  epack[pos] = ((unsigned)etype[e] << 17) | (unsigned)esrc[e];
}

// ---------------- per-pass aggregation: s[n, t*128+d] = sum h[src] (bf16 out) ----------------
// 2-deep rotating load pipeline: hv for edge j+1 issued before accumulating edge j.
__global__ __launch_bounds__(256) void agg_k(const int* __restrict__ rowptr,
                                             const unsigned* __restrict__ epack,
                                             const unsigned short* __restrict__ H,
                                             unsigned short* __restrict__ s) {
  int n = blockIdx.x * 4 + (threadIdx.x >> 6);
  int lane = threadIdx.x & 63;
  int beg = rowptr[n], end = rowptr[n + 1];
  const unsigned short* hbase = H + lane * 2;
  float a0 = 0.f, a1 = 0.f, b0 = 0.f, b1 = 0.f;
  float c0 = 0.f, c1 = 0.f, d0 = 0.f, d1 = 0.f;
#define ACCUM(P, HV)                                              \
  {                                                               \
    int t_ = (int)((P) >> 17);                                    \
    float v0_ = bf2f((unsigned short)((HV) & 0xffffu));           \
    float v1_ = bf2f((unsigned short)((HV) >> 16));               \
    if (t_ == 0)      { a0 += v0_; a1 += v1_; }                   \
    else if (t_ == 1) { b0 += v0_; b1 += v1_; }                   \
    else if (t_ == 2) { c0 += v0_; c1 += v1_; }                   \
    else              { d0 += v0_; d1 += v1_; }                   \
  }
  for (int base = beg; base < end; base += 64) {
    int cnt = end - base;
    if (cnt > 64) cnt = 64;
    int mye = base + lane;
    unsigned ep = (mye < end) ? epack[mye] : 0u;  // coalesced pre-load
    if (cnt > 0) {
      unsigned p = (unsigned)__shfl((int)ep, 0);
      unsigned hv = *(const unsigned*)&hbase[(size_t)(p & 0x1FFFFu) * 128];
      for (int j = 1; j < cnt; j++) {
        unsigned pn = (unsigned)__shfl((int)ep, j);
        unsigned hvn = *(const unsigned*)&hbase[(size_t)(pn & 0x1FFFFu) * 128];
        ACCUM(p, hv);
        p = pn;
        hv = hvn;
      }
      ACCUM(p, hv);
    }
  }
#undef ACCUM
  unsigned short* srow = s + (size_t)n * 512;
  *(unsigned*)&srow[0 * 128 + lane * 2] = pack2(a0, a1);
  *(unsigned*)&srow[1 * 128 + lane * 2] = pack2(b0, b1);
  *(unsigned*)&srow[2 * 128 + lane * 2] = pack2(c0, c1);
  *(unsigned*)&srow[3 * 128 + lane * 2] = pack2(d0, d1);
}

// ---------------- fused m+GRU GEMM: 64 rows/block, double-buffered staging (R10) ----------
// phase B: m = relu(s @ Wb^T + cnt*b_msg) -> LDS mT (stride 264)
// phase C: GRU GEMM [m | H] @ Wgru^T (cols gate-interleaved 4*d+g), 2 jh halves,
//          quad-transpose GRU epilogue -> Hn.
__global__ __launch_bounds__(256, 2) void mgru_k(
    const unsigned short* __restrict__ s, const float* __restrict__ cnt,
    const unsigned short* __restrict__ Hc, unsigned short* __restrict__ Hn,
    const unsigned short* __restrict__ Wb, const unsigned short* __restrict__ Wgru,
    const float* __restrict__ bmsg, const float* __restrict__ biasg) {
  __shared__ __align__(16) unsigned short mT[64 * 264];   // 33792 B
  __shared__ __align__(16) unsigned short stg[2][10240];  // per unit: As[0,2048) Ws[2048,10240)
  int i0 = blockIdx.x * 64;
  int tid = threadIdx.x, lane = tid & 63, w = tid >> 6;
  int wi = w >> 1, wj = w & 1;
  int q = lane >> 4, r = lane & 15;
  int srow = tid >> 2, scol = (tid & 3) * 8;

  const unsigned short* sP = s + (size_t)(i0 + srow) * 512 + scol;
  const unsigned short* WbP = Wb + (size_t)srow * 512 + scol;
  const unsigned short* WgP = Wgru + (size_t)srow * 384 + scol;

  // ---- phase B: 16 windows (BK=32), dbuf ----
  f32x4 accm[2][8];
#pragma unroll
  for (int a = 0; a < 2; a++)
#pragma unroll
    for (int b = 0; b < 8; b++) accm[a][b] = f32x4{0.f, 0.f, 0.f, 0.f};

  // pre-stage ks=0
  cp16(&stg[0][w * 512], sP);
#pragma unroll
  for (int c = 0; c < 4; c++)
    cp16(&stg[0][2048 + c * 2048 + w * 512], WbP + (size_t)(c * 64) * 512);
  __syncthreads();

  for (int ks = 0; ks < 16; ks++) {
    int b = ks & 1;
    if (ks < 15) {
      int nb = b ^ 1;
      cp16(&stg[nb][w * 512], sP + (ks + 1) * 32);
#pragma unroll
      for (int c = 0; c < 4; c++)
        cp16(&stg[nb][2048 + c * 2048 + w * 512],
             WbP + (size_t)(c * 64) * 512 + (ks + 1) * 32);
    }
    bfrag af[2];
#pragma unroll
    for (int rt = 0; rt < 2; rt++)
      af[rt] = *(const bfrag*)&stg[b][(wi * 32 + rt * 16 + r) * 32 + q * 8];
#pragma unroll
    for (int ct = 0; ct < 8; ct++) {
      bfrag bfr = *(const bfrag*)&stg[b][2048 + (wj * 128 + ct * 16 + r) * 32 + q * 8];
#pragma unroll
      for (int rt = 0; rt < 2; rt++)
        accm[rt][ct] =
            __builtin_amdgcn_mfma_f32_16x16x32_bf16(af[rt], bfr, accm[rt][ct], 0, 0, 0);
    }
    __syncthreads();
  }

  // H fragments for phase C k=256..383 (issue early)
  bfrag hfr[4][2];
#pragma unroll
  for (int kh = 0; kh < 4; kh++)
#pragma unroll
    for (int rt = 0; rt < 2; rt++)
      hfr[kh][rt] =
          *(const bfrag*)&Hc[(size_t)(i0 + wi * 32 + rt * 16 + r) * 128 + kh * 32 + q * 8];

  // ---- m epilogue: + cnt*b_msg, relu -> mT ----
#pragma unroll
  for (int ct = 0; ct < 8; ct++) {
    int j = wj * 128 + ct * 16 + r;
    float b0 = bmsg[j], b1 = bmsg[256 + j], b2 = bmsg[512 + j], b3 = bmsg[768 + j];
#pragma unroll
    for (int rt = 0; rt < 2; rt++) {
#pragma unroll
      for (int reg = 0; reg < 4; reg++) {
        int il = wi * 32 + rt * 16 + q * 4 + reg;
        float4 c4 = *(const float4*)&cnt[(size_t)(i0 + il) * 4];
        float v = accm[rt][ct][reg] + c4.x * b0 + c4.y * b1 + c4.z * b2 + c4.w * b3;
        v = v > 0.f ? v : 0.f;
        mT[il * 264 + j] = f2bf(v);
      }
    }
  }
  // pre-stage phase-C window v=0 (jh=0, ks=0)
#pragma unroll
  for (int c = 0; c < 4; c++)
    cp16(&stg[0][2048 + c * 2048 + w * 512], WgP + (size_t)(c * 64) * 384);
  __syncthreads();  // publishes mT + drains v0

  // ---- phase C: 24 windows (2 jh x 12 ks), dbuf ----
  for (int jh = 0; jh < 2; jh++) {
    f32x4 acc[2][8];
#pragma unroll
    for (int a = 0; a < 2; a++)
#pragma unroll
      for (int b = 0; b < 8; b++) acc[a][b] = f32x4{0.f, 0.f, 0.f, 0.f};

    for (int ks = 0; ks < 12; ks++) {
      int v = jh * 12 + ks;
      int b = v & 1;
      if (v < 23) {
        int nb = b ^ 1;
        int nv = v + 1;
        int njh = nv >= 12 ? 1 : 0;
        int nks = nv - njh * 12;
#pragma unroll
        for (int c = 0; c < 4; c++)
          cp16(&stg[nb][2048 + c * 2048 + w * 512],
               WgP + (size_t)(njh * 256 + c * 64) * 384 + nks * 32);
      }
      bfrag af[2];
#pragma unroll
      for (int rt = 0; rt < 2; rt++)
        af[rt] = (ks < 8)
                     ? *(const bfrag*)&mT[(wi * 32 + rt * 16 + r) * 264 + ks * 32 + q * 8]
                     : hfr[ks - 8][rt];
#pragma unroll
      for (int ct = 0; ct < 8; ct++) {
        bfrag bfr = *(const bfrag*)&stg[b][2048 + (wj * 128 + ct * 16 + r) * 32 + q * 8];
#pragma unroll
        for (int rt = 0; rt < 2; rt++)
          acc[rt][ct] =
              __builtin_amdgcn_mfma_f32_16x16x32_bf16(af[rt], bfr, acc[rt][ct], 0, 0, 0);
      }
      __syncthreads();
    }

    // GRU epilogue: cols are 4*d+g; quad transpose gives each lane its 4 gates
    int rr = r & 3;
    bool s1 = (lane & 1) != 0, s2 = (lane & 2) != 0;
#pragma unroll
    for (int ct = 0; ct < 8; ct++) {
      float bias = biasg[jh * 256 + wj * 128 + ct * 16 + r];
      int d = jh * 64 + wj * 32 + ct * 4 + (r >> 2);
#pragma unroll
      for (int rt = 0; rt < 2; rt++) {
        float v0 = acc[rt][ct][0] + bias;
        float v1 = acc[rt][ct][1] + bias;
        float v2 = acc[rt][ct][2] + bias;
        float v3 = acc[rt][ct][3] + bias;
        float t, rcv;
        t = s1 ? v0 : v1; rcv = __shfl_xor(t, 1);
        v0 = s1 ? rcv : v0; v1 = s1 ? v1 : rcv;
        t = s1 ? v2 : v3; rcv = __shfl_xor(t, 1);
        v2 = s1 ? rcv : v2; v3 = s1 ? v3 : rcv;
        t = s2 ? v0 : v2; rcv = __shfl_xor(t, 2);
        v0 = s2 ? rcv : v0; v2 = s2 ? v2 : rcv;
        t = s2 ? v1 : v3; rcv = __shfl_xor(t, 2);
        v1 = s2 ? rcv : v1; v3 = s2 ? v3 : rcv;
        int i = i0 + wi * 32 + rt * 16 + q * 4 + rr;
        size_t hoff = (size_t)i * 128 + d;
        float hold = bf2f(Hc[hoff]);
        float rg = sigm(v0), zg = sigm(v1);
        float ng = tanhf(v2 + rg * v3);
        Hn[hoff] = f2bf((1.f - zg) * ng + zg * hold);
      }
    }
  }
}

// ---------------- readout ----------------
__global__ __launch_bounds__(256) void gate_k(const unsigned short* __restrict__ H,
                                              const float* __restrict__ Wg,
                                              const float* __restrict__ bg,
                                              float* __restrict__ gate) {
  __shared__ float wg[128];
  if (threadIdx.x < 128) wg[threadIdx.x] = Wg[threadIdx.x];
  __syncthreads();
  int g = threadIdx.x >> 4, sub = threadIdx.x & 15;
  int n = blockIdx.x * 16 + g;
  const unsigned short* hr = H + (size_t)n * 128;
  float p = 0.f;
  for (int k = sub; k < 128; k += 16) p += bf2f(hr[k]) * wg[k];
  p += __shfl_xor(p, 1);
  p += __shfl_xor(p, 2);
  p += __shfl_xor(p, 4);
  p += __shfl_xor(p, 8);
  if (sub == 0) gate[n] = sigm(p + bg[0]);
}

// per-graph: gsum[g] = sum gate_n * h_n (fp32), sg[g] = sum gate_n
__global__ __launch_bounds__(256) void gsum_k(const unsigned short* __restrict__ H,
                                              const float* __restrict__ gate,
                                              const int* __restrict__ ptr,
                                              float* __restrict__ gsum,
                                              float* __restrict__ sg) {
  int g = blockIdx.x * 4 + (threadIdx.x >> 6);
  int lane = threadIdx.x & 63;
  int start = ptr[g], end = ptr[g + 1];
  float a0 = 0.f, a1 = 0.f, gs = 0.f;
  for (int n = start; n < end; n++) {
    float gt = gate[n];
    unsigned hv = *(const unsigned*)&H[(size_t)n * 128 + lane * 2];
    a0 += gt * bf2f((unsigned short)(hv & 0xffffu));
    a1 += gt * bf2f((unsigned short)(hv >> 16));
    gs += gt;
  }
  gsum[(size_t)g * 128 + lane * 2] = a0;
  gsum[(size_t)g * 128 + lane * 2 + 1] = a1;
  if (lane == 0) sg[g] = gs;
}

// z[j] = gsum[g] . WcT[:,j] + sg[g]*cvec[j] + bias[j]
__global__ __launch_bounds__(256) void zfinal_k(const float* __restrict__ gsum,
                                                const float* __restrict__ sg,
                                                const float* __restrict__ WcT,
                                                const float* __restrict__ cvec,
                                                const float* __restrict__ bloc,
                                                const float* __restrict__ blv,
                                                float* __restrict__ out) {
  __shared__ float gs[128];
  __shared__ float sgs;
  int g = blockIdx.x;
  int j = threadIdx.x;
  if (j < 128) gs[j] = gsum[(size_t)g * 128 + j];
  if (j == 0) sgs = sg[g];
  __syncthreads();
  float acc = (j < 128 ? bloc[j] : blv[j - 128]) + sgs * cvec[j];
  for (int d = 0; d < 128; d++) acc += gs[d] * WcT[d * 256 + j];
  size_t o = (j < 128) ? ((size_t)g * 128 + j)
                       : ((size_t)GG * 128 + (size_t)g * 128 + (j - 128));
  out[o] = acc;
}

extern "C" void kernel_launch(void* const* d_in, const int* in_sizes, int n_in,
                              void* d_out, int out_size, void* d_ws, size_t ws_size,
                              hipStream_t stream) {
  const int* node_types = (const int*)d_in[0];
  const int* esrc = (const int*)d_in[1];
  const int* edst = (const int*)d_in[2];
  const int* etype = (const int*)d_in[3];
  const int* ptr = (const int*)d_in[4];
  const float* emb = (const float*)d_in[5];
  const float* Wmsg = (const float*)d_in[6];
  const float* bmsg = (const float*)d_in[7];
  const float* Wih = (const float*)d_in[8];
  const float* Whh = (const float*)d_in[9];
  const float* bih = (const float*)d_in[10];
  const float* bhh = (const float*)d_in[11];
  const float* Wg = (const float*)d_in[12];
  const float* bg = (const float*)d_in[13];
  const float* Wn2g = (const float*)d_in[14];
  const float* bn2g = (const float*)d_in[15];
  const float* Wloc = (const float*)d_in[16];
  const float* bloc = (const float*)d_in[17];
  const float* Wlv = (const float*)d_in[18];
  const float* blv = (const float*)d_in[19];
  float* out = (float*)d_out;

  char* ws = (char*)d_ws;
  size_t off = 0;
  unsigned short* s = (unsigned short*)(ws);  // N x 512 bf16
  off += (size_t)NN * 512 * 2;
  unsigned short* H0 = (unsigned short*)(ws + off);  // N x 128 bf16
  off += (size_t)NN * 128 * 2;
  unsigned short* H1 = (unsigned short*)(ws + off);
  off += (size_t)NN * 128 * 2;
  float* cnt = (float*)(ws + off);
  off += (size_t)NN * 4 * 4;
  int* cnti = (int*)(ws + off);
  off += (size_t)NN * 4 * 4;
  int* deg = (int*)(ws + off);
  off += (size_t)NN * 4;
  int* rowptr = (int*)(ws + off);
  off += (size_t)(NN + 64) * 4;
  int* cursor = (int*)(ws + off);
  off += (size_t)NN * 4;
  unsigned* epack = (unsigned*)(ws + off);
  off += (size_t)EE * 4;
  float* gate = (float*)(ws + off);
  off += (size_t)NN * 4;
  float* gsum = (float*)(ws + off);
  off += (size_t)GG * 128 * 4;
  float* sg = (float*)(ws + off);
  off += (size_t)GG * 4;
  float* WcT = (float*)(ws + off);
  off += 128 * 256 * 4;
  float* cvec = (float*)(ws + off);
  off += 256 * 4;
  unsigned short* Wb = (unsigned short*)(ws + off);
  off += 256 * 512 * 2;
  unsigned short* Wgru = (unsigned short*)(ws + off);
  off += 512 * 384 * 2;
  float* biasg = (float*)(ws + off);
  off += 512 * 4;
  // total ~214 MB < 256 MiB ws

  hipMemsetAsync(cnti, 0, (size_t)NN * 16, stream);
  prep_wb<<<512, 256, 0, stream>>>(Wmsg, Wb);
  prep_wgru<<<768, 256, 0, stream>>>(Wih, Whh, Wgru);
  prep_bias<<<2, 256, 0, stream>>>(bih, bhh, biasg);
  compose_k<<<128, 256, 0, stream>>>(Wloc, Wlv, Wn2g, WcT);
  cvec_k<<<1, 256, 0, stream>>>(Wloc, Wlv, bn2g, cvec);
  init_h<<<NN * 128 / 256, 256, 0, stream>>>(node_types, emb, H0);
  cnt4_k<<<EE / 256, 256, 0, stream>>>(edst, etype, cnti);
  degsum_k<<<NN / 256, 256, 0, stream>>>(cnti, deg, cnt);
  scan_k<<<1, 1024, 0, stream>>>(deg, rowptr, cursor);
  fill_k<<<EE / 256, 256, 0, stream>>>(esrc, edst, etype, cursor, epack);

  unsigned short* Hc = H0;
  unsigned short* Hn = H1;
  for (int p = 0; p < NPASS; p++) {
    agg_k<<<NN / 4, 256, 0, stream>>>(rowptr, epack, Hc, s);
    mgru_k<<<NN / 64, 256, 0, stream>>>(s, cnt, Hc, Hn, Wb, Wgru, bmsg, biasg);
    unsigned short* tmp = Hc; Hc = Hn; Hn = tmp;
  }

  gate_k<<<NN / 16, 256, 0, stream>>>(Hc, Wg, bg, gate);
  gsum_k<<<GG / 4, 256, 0, stream>>>(Hc, gate, ptr, gsum, sg);
  zfinal_k<<<GG, 256, 0, stream>>>(gsum, sg, WcT, cvec, bloc, blv, out);
}